// Round 5
// baseline (66.941 us; speedup 1.0000x reference)
//
#include <hip/hip_runtime.h>

// LDDMM Hamiltonian evolution, closed-form gradients of
// H = sum_ij exp(-||x_i-x_j||^2/sigma^2) <m_i,m_j>, sigma=0.1:
//   out0 = -dH/dpos = (4/sigma^2) * sum_j K_ij (m_i.m_j)(x_i-x_j)
//   out1 =  dH/dmom = 2 * sum_j K_ij m_j
//
// R5: i-per-thread + dot-product expansion. Prep kernel packs 32B records
// [X,Y,Z,-|X|^2, mx,my,mz,0] (X = pos * sqrt(100*log2 e), so
// K = exp2(2<Xi,Xj> - |Xi|^2 - |Xj|^2) via one raw v_exp_f32).
// Inner loop: 15 FMA-class VALU + 1 exp + 2x ds_read_b128 with explicit
// next-record register prefetch (fixes R4's no-prefetch, VGPR=28 codegen).
// G=64 j-segments -> 2048 blocks = 8 waves/SIMD. Force folds post-loop:
// F = Xi*Sw - Swx. Partials -> ws, deterministic reduce.

constexpr int BLOCK = 256;
constexpr double S_D       = 12.011224087864498;     // sqrt(100*log2(e))
constexpr float  SCALE_POS = (float)S_D;
constexpr float  SCALE_F   = (float)(400.0 / S_D);   // (4/sigma^2)/S

__device__ __forceinline__ float fast_exp2(float x) {
#if __has_builtin(__builtin_amdgcn_exp2f)
    return __builtin_amdgcn_exp2f(x);
#else
    float r; asm("v_exp_f32 %0, %1" : "=v"(r) : "v"(x)); return r;
#endif
}

__global__ __launch_bounds__(BLOCK)
void lddmm_prep(const float* __restrict__ mom, const float* __restrict__ pos,
                float4* __restrict__ rec, int N)
{
    const int i = blockIdx.x * blockDim.x + threadIdx.x;
    if (i >= N) return;
    const float X = SCALE_POS * pos[3 * i + 0];
    const float Y = SCALE_POS * pos[3 * i + 1];
    const float Z = SCALE_POS * pos[3 * i + 2];
    rec[2 * i + 0] = make_float4(X, Y, Z, -fmaf(X, X, fmaf(Y, Y, Z * Z)));
    rec[2 * i + 1] = make_float4(mom[3 * i + 0], mom[3 * i + 1], mom[3 * i + 2], 0.f);
}

__global__ __launch_bounds__(BLOCK)
void lddmm_main(const float4* __restrict__ rec, float* __restrict__ part,
                int N, int G)
{
    extern __shared__ float4 srec[];                 // 2*(jlen+1) float4
    const int jlen = N / G;                          // N % G == 0 (N=8192)
    const int bid  = blockIdx.x;
    const int seg  = bid % G;
    const int ib   = bid / G;
    const int tid  = threadIdx.x;
    const int i    = ib * BLOCK + tid;
    const int j0   = seg * jlen;

    // stage this segment's records (coalesced float4), plus one zero pad
    for (int r = tid; r < 2 * jlen; r += BLOCK) srec[r] = rec[2 * j0 + r];
    if (tid == 0) {
        srec[2 * jlen + 0] = make_float4(0.f, 0.f, 0.f, 0.f);
        srec[2 * jlen + 1] = make_float4(0.f, 0.f, 0.f, 0.f);  // m=0 -> zero contrib
    }
    __syncthreads();

    // own-i data from packed records
    const int ii = (i < N) ? i : 0;
    const float4 r0 = rec[2 * ii + 0];               // X,Y,Z,-|X|^2
    const float4 r1 = rec[2 * ii + 1];               // mx,my,mz,0
    const float X2 = 2.f * r0.x, Y2 = 2.f * r0.y, Z2 = 2.f * r0.z;
    const float Di = r0.w;

    float Sw = 0.f, Swx = 0.f, Swy = 0.f, Swz = 0.f;
    float gx = 0.f, gy = 0.f, gz = 0.f;

    float4 a0 = srec[0], a1 = srec[1];
    #pragma unroll 4
    for (int r = 0; r < jlen; ++r) {
        const float4 n0 = srec[2 * r + 2];           // prefetch next record
        const float4 n1 = srec[2 * r + 3];
        float t = fmaf(X2, a0.x, Di);
        t = fmaf(Y2, a0.y, t);
        t = fmaf(Z2, a0.z, t);
        const float arg = t + a0.w;                  // = -||Xi-Xj||^2
        const float e   = fast_exp2(arg);            // = exp(-100*||xi-xj||^2)
        const float md  = fmaf(r1.x, a1.x, fmaf(r1.y, a1.y, r1.z * a1.z));
        const float w   = e * md;
        Sw  += w;
        Swx = fmaf(w, a0.x, Swx);
        Swy = fmaf(w, a0.y, Swy);
        Swz = fmaf(w, a0.z, Swz);
        gx  = fmaf(e, a1.x, gx);
        gy  = fmaf(e, a1.y, gy);
        gz  = fmaf(e, a1.z, gz);
        a0 = n0; a1 = n1;
    }

    if (i < N) {
        float* p = part + (size_t)seg * 6 * N;       // [seg][comp][N] coalesced
        p[0 * N + i] = fmaf(r0.x, Sw, -Swx);         // Xi*Sw - sum w*Xj
        p[1 * N + i] = fmaf(r0.y, Sw, -Swy);
        p[2 * N + i] = fmaf(r0.z, Sw, -Swz);
        p[3 * N + i] = gx;
        p[4 * N + i] = gy;
        p[5 * N + i] = gz;
    }
}

__global__ __launch_bounds__(BLOCK)
void lddmm_reduce(const float* __restrict__ part, float* __restrict__ out,
                  int N, int G)
{
    const int i = blockIdx.x * blockDim.x + threadIdx.x;
    if (i >= N) return;
    float s0 = 0.f, s1 = 0.f, s2 = 0.f, s3 = 0.f, s4 = 0.f, s5 = 0.f;
    for (int g = 0; g < G; ++g) {
        const float* p = part + (size_t)g * 6 * N;
        s0 += p[0 * N + i];
        s1 += p[1 * N + i];
        s2 += p[2 * N + i];
        s3 += p[3 * N + i];
        s4 += p[4 * N + i];
        s5 += p[5 * N + i];
    }
    out[i * 3 + 0] = SCALE_F * s0;
    out[i * 3 + 1] = SCALE_F * s1;
    out[i * 3 + 2] = SCALE_F * s2;
    float* o2 = out + (size_t)N * 3;
    o2[i * 3 + 0] = 2.0f * s3;
    o2[i * 3 + 1] = 2.0f * s4;
    o2[i * 3 + 2] = 2.0f * s5;
}

extern "C" void kernel_launch(void* const* d_in, const int* in_sizes, int n_in,
                              void* d_out, int out_size, void* d_ws, size_t ws_size,
                              hipStream_t stream) {
    const float* mom = (const float*)d_in[0];
    const float* pos = (const float*)d_in[1];
    float* out = (float*)d_out;
    const int N = in_sizes[0] / 3;   // B=1, D=3

    const size_t rec_bytes = (size_t)N * 2 * sizeof(float4);   // 256 KB @ N=8192
    int G = 64;                                                // 8 waves/SIMD
    while (G > 1 && rec_bytes + (size_t)G * 6 * N * sizeof(float) > ws_size) G >>= 1;

    float4* rec  = (float4*)d_ws;
    float*  part = (float*)((char*)d_ws + rec_bytes);
    const int jlen  = N / G;
    const size_t shmem = (size_t)(2 * jlen + 2) * sizeof(float4);
    const int nib = (N + BLOCK - 1) / BLOCK;

    lddmm_prep<<<dim3(nib), dim3(BLOCK), 0, stream>>>(mom, pos, rec, N);
    lddmm_main<<<dim3(nib * G), dim3(BLOCK), shmem, stream>>>(rec, part, N, G);
    lddmm_reduce<<<dim3(nib), dim3(BLOCK), 0, stream>>>(part, out, N, G);
}

// Round 6
// 60.713 us; speedup vs baseline: 1.1026x; 1.1026x over previous
//
#include <hip/hip_runtime.h>
#include <stdint.h>

// LDDMM Hamiltonian evolution, closed-form gradients of
// H = sum_ij exp(-||x_i-x_j||^2/sigma^2) <m_i,m_j>, sigma=0.1:
//   out0 = -dH/dpos = (4/sigma^2) * sum_j K_ij (m_i.m_j)(x_i-x_j)
//   out1 =  dH/dmom = 2 * sum_j K_ij m_j
//
// R6: i-per-thread with the wave-uniform j-stream in SGPRs via s_load.
// rec[] packs 32B/point: [X,Y,Z,-|X|^2][mx,my,mz,0], X = pos*sqrt(100 log2 e)
// so K = exp2(2<Xi,Xj> - |Xi|^2 - |Xj|^2). The j-record pointer is cast to
// the CONSTANT address space (addrspace 4, composable_kernel uintptr_t trick)
// at a wave-uniform address -> compiler selects s_load_dwordx8: zero LDS,
// zero barriers, zero vector-memory in the loop. Inner loop = 15 VALU + 1
// v_exp_f32, each instr reads <=1 SGPR (ISA-legal). G=64 j-segments ->
// 2048 blocks = 8 blocks/CU. Partials -> ws, deterministic reduce.

constexpr int BLOCK = 256;
constexpr double S_D       = 12.011224087864498;     // sqrt(100*log2(e))
constexpr float  SCALE_POS = (float)S_D;
constexpr float  SCALE_F   = (float)(400.0 / S_D);   // (4/sigma^2)/S

typedef float f4 __attribute__((ext_vector_type(4)));
typedef const __attribute__((address_space(4))) f4* crec_t;   // constant addrspace

__device__ __forceinline__ float fast_exp2(float x) {
#if __has_builtin(__builtin_amdgcn_exp2f)
    return __builtin_amdgcn_exp2f(x);
#else
    return exp2f(x);
#endif
}

__global__ __launch_bounds__(BLOCK)
void lddmm_prep(const float* __restrict__ mom, const float* __restrict__ pos,
                f4* __restrict__ rec, int N)
{
    const int i = blockIdx.x * blockDim.x + threadIdx.x;
    if (i >= N) return;
    const float X = SCALE_POS * pos[3 * i + 0];
    const float Y = SCALE_POS * pos[3 * i + 1];
    const float Z = SCALE_POS * pos[3 * i + 2];
    f4 a; a[0] = X; a[1] = Y; a[2] = Z; a[3] = -fmaf(X, X, fmaf(Y, Y, Z * Z));
    f4 b; b[0] = mom[3 * i + 0]; b[1] = mom[3 * i + 1]; b[2] = mom[3 * i + 2]; b[3] = 0.f;
    rec[2 * i + 0] = a;
    rec[2 * i + 1] = b;
}

__global__ __launch_bounds__(BLOCK)
void lddmm_main(const f4* __restrict__ rec, float* __restrict__ part, int N, int G)
{
    const int bid  = blockIdx.x;
    const int seg  = bid % G;
    const int ib   = bid / G;
    const int tid  = threadIdx.x;
    const int i    = ib * BLOCK + tid;
    const int jlen = N / G;                          // G chosen to divide N
    const int j0   = seg * jlen;

    // own-i data (per-lane coalesced vector loads)
    const int ii = (i < N) ? i : 0;
    const f4 r0 = rec[2 * ii + 0];                   // X,Y,Z,-|X|^2
    const f4 r1 = rec[2 * ii + 1];                   // mx,my,mz,0
    const float X2 = 2.f * r0[0], Y2 = 2.f * r0[1], Z2 = 2.f * r0[2];
    const float Di = r0[3];
    const float mxi = r1[0], myi = r1[1], mzi = r1[2];

    // wave-uniform j-stream through the scalar path (constant addrspace)
    crec_t cr = (crec_t)(uintptr_t)(rec + 2 * (size_t)j0);

    float Sw = 0.f, Swx = 0.f, Swy = 0.f, Swz = 0.f;
    float gx = 0.f, gy = 0.f, gz = 0.f;

    #pragma unroll 4
    for (int r = 0; r < jlen; ++r) {
        const f4 a0 = cr[2 * r + 0];                 // s_load_dwordx8 (SGPRs)
        const f4 a1 = cr[2 * r + 1];
        float t = fmaf(X2, a0[0], Di);
        t = fmaf(Y2, a0[1], t);
        t = fmaf(Z2, a0[2], t);
        const float e  = fast_exp2(t + a0[3]);       // = exp(-100*||xi-xj||^2)
        const float md = fmaf(mxi, a1[0], fmaf(myi, a1[1], mzi * a1[2]));
        const float w  = e * md;
        Sw  += w;
        Swx = fmaf(w, a0[0], Swx);
        Swy = fmaf(w, a0[1], Swy);
        Swz = fmaf(w, a0[2], Swz);
        gx  = fmaf(e, a1[0], gx);
        gy  = fmaf(e, a1[1], gy);
        gz  = fmaf(e, a1[2], gz);
    }

    if (i < N) {
        float* p = part + (size_t)seg * 6 * N;       // [seg][comp][N] coalesced
        p[0 * N + i] = fmaf(r0[0], Sw, -Swx);        // Xi*Sw - sum w*Xj
        p[1 * N + i] = fmaf(r0[1], Sw, -Swy);
        p[2 * N + i] = fmaf(r0[2], Sw, -Swz);
        p[3 * N + i] = gx;
        p[4 * N + i] = gy;
        p[5 * N + i] = gz;
    }
}

__global__ __launch_bounds__(BLOCK)
void lddmm_reduce(const float* __restrict__ part, float* __restrict__ out,
                  int N, int G)
{
    const int i = blockIdx.x * blockDim.x + threadIdx.x;
    if (i >= N) return;
    float s0 = 0.f, s1 = 0.f, s2 = 0.f, s3 = 0.f, s4 = 0.f, s5 = 0.f;
    for (int g = 0; g < G; ++g) {
        const float* p = part + (size_t)g * 6 * N;
        s0 += p[0 * N + i];
        s1 += p[1 * N + i];
        s2 += p[2 * N + i];
        s3 += p[3 * N + i];
        s4 += p[4 * N + i];
        s5 += p[5 * N + i];
    }
    out[i * 3 + 0] = SCALE_F * s0;
    out[i * 3 + 1] = SCALE_F * s1;
    out[i * 3 + 2] = SCALE_F * s2;
    float* o2 = out + (size_t)N * 3;
    o2[i * 3 + 0] = 2.0f * s3;
    o2[i * 3 + 1] = 2.0f * s4;
    o2[i * 3 + 2] = 2.0f * s5;
}

extern "C" void kernel_launch(void* const* d_in, const int* in_sizes, int n_in,
                              void* d_out, int out_size, void* d_ws, size_t ws_size,
                              hipStream_t stream) {
    const float* mom = (const float*)d_in[0];
    const float* pos = (const float*)d_in[1];
    float* out = (float*)d_out;
    const int N = in_sizes[0] / 3;   // B=1, D=3

    const size_t rec_bytes = (size_t)N * 2 * sizeof(f4);       // 256 KB @ N=8192
    int G = 64;                                                // 8 blocks/CU
    while (G > 1 && ((N % G) != 0 ||
           rec_bytes + (size_t)G * 6 * N * sizeof(float) > ws_size)) G >>= 1;

    f4*    rec  = (f4*)d_ws;
    float* part = (float*)((char*)d_ws + rec_bytes);
    const int nib = (N + BLOCK - 1) / BLOCK;

    lddmm_prep<<<dim3(nib), dim3(BLOCK), 0, stream>>>(mom, pos, rec, N);
    lddmm_main<<<dim3(nib * G), dim3(BLOCK), 0, stream>>>(rec, part, N, G);
    lddmm_reduce<<<dim3(nib), dim3(BLOCK), 0, stream>>>(part, out, N, G);
}

// Round 7
// 53.996 us; speedup vs baseline: 1.2397x; 1.1244x over previous
//
#include <hip/hip_runtime.h>

// LDDMM Hamiltonian evolution, closed-form gradients of
// H = sum_ij exp(-||x_i-x_j||^2/sigma^2) <m_i,m_j>, sigma=0.1:
//   out0 = -dH/dpos = (4/sigma^2) * sum_j K_ij (m_i.m_j)(x_i-x_j)
//   out1 =  dH/dmom = 2 * sum_j K_ij m_j
//
// R7: i-per-thread with MI=2 i's per thread (amortizes j-record LDS read +
// loop overhead over 2 pairs; 2x compute per load for latency hiding).
// Dot-form: record [X,Y,Z,-|X|^2][mx,my,mz,0], X = pos*sqrt(100*log2 e),
// K = exp2(2<Xi,Xj> - |Xi|^2 - |Xj|^2), raw v_exp_f32 (no denorm guard).
// NO manual prefetch rotation (R5's 8 v_mov/iter mistake) — unroll 4 +
// __launch_bounds__(256,4) (VGPR cap 128) lets the compiler pipeline.
// Stage scales pos directly from global (prep kernel eliminated; 2 kernels).
// G=64 j-segments; partials -> ws [seg][comp][N]; deterministic reduce.

constexpr int BLOCK = 256;
constexpr int MI    = 2;                             // i-points per thread
constexpr int IPB   = BLOCK * MI;                    // 512 i per block
constexpr double S_D       = 12.011224087864498;     // sqrt(100*log2(e))
constexpr float  SCALE_POS = (float)S_D;
constexpr float  SCALE_F   = (float)(400.0 / S_D);   // (4/sigma^2)/S

__device__ __forceinline__ float fast_exp2(float x) {
#if __has_builtin(__builtin_amdgcn_exp2f)
    return __builtin_amdgcn_exp2f(x);
#else
    return exp2f(x);
#endif
}

__global__ __launch_bounds__(BLOCK, 4)
void lddmm_main(const float* __restrict__ mom, const float* __restrict__ pos,
                float* __restrict__ part, int N, int G)
{
    extern __shared__ float4 srec[];                 // 2*jlen float4
    const int jlen = N / G;                          // G divides N
    const int bid  = blockIdx.x;
    const int seg  = bid % G;
    const int ib   = bid / G;
    const int tid  = threadIdx.x;
    const int j0   = seg * jlen;

    // ---- stage this j-segment straight from pos/mom (scaled) ----
    for (int r = tid; r < jlen; r += BLOCK) {
        const int jg = j0 + r;
        const float X = SCALE_POS * pos[3 * jg + 0];
        const float Y = SCALE_POS * pos[3 * jg + 1];
        const float Z = SCALE_POS * pos[3 * jg + 2];
        srec[2 * r + 0] = make_float4(X, Y, Z, -fmaf(X, X, fmaf(Y, Y, Z * Z)));
        srec[2 * r + 1] = make_float4(mom[3 * jg + 0], mom[3 * jg + 1],
                                      mom[3 * jg + 2], 0.f);
    }
    __syncthreads();

    // ---- own i data (2 i's per thread), computed from global ----
    const int ia = ib * IPB + tid;
    const int ib2 = ia + BLOCK;
    const int ca = (ia  < N) ? ia  : 0;
    const int cb = (ib2 < N) ? ib2 : 0;

    float X2[MI], Y2[MI], Z2[MI], Di[MI], mx[MI], my[MI], mz[MI];
    const int cc[MI] = {ca, cb};
    #pragma unroll
    for (int u = 0; u < MI; ++u) {
        const float X = SCALE_POS * pos[3 * cc[u] + 0];
        const float Y = SCALE_POS * pos[3 * cc[u] + 1];
        const float Z = SCALE_POS * pos[3 * cc[u] + 2];
        X2[u] = 2.f * X; Y2[u] = 2.f * Y; Z2[u] = 2.f * Z;
        Di[u] = -fmaf(X, X, fmaf(Y, Y, Z * Z));
        mx[u] = mom[3 * cc[u] + 0];
        my[u] = mom[3 * cc[u] + 1];
        mz[u] = mom[3 * cc[u] + 2];
    }

    float Sw[MI] = {}, Sx[MI] = {}, Sy[MI] = {}, Sz[MI] = {};
    float gx[MI] = {}, gy[MI] = {}, gz[MI] = {};

    // ---- main loop: 1 j-record (2x ds_read_b128 broadcast) -> 2 pairs ----
    #pragma unroll 4
    for (int r = 0; r < jlen; ++r) {
        const float4 a0 = srec[2 * r + 0];
        const float4 a1 = srec[2 * r + 1];
        #pragma unroll
        for (int u = 0; u < MI; ++u) {
            float t = fmaf(X2[u], a0.x, Di[u]);
            t = fmaf(Y2[u], a0.y, t);
            t = fmaf(Z2[u], a0.z, t);
            const float e  = fast_exp2(t + a0.w);    // exp(-100*||xi-xj||^2)
            const float md = fmaf(mx[u], a1.x, fmaf(my[u], a1.y, mz[u] * a1.z));
            const float w  = e * md;
            Sw[u] += w;
            Sx[u] = fmaf(w, a0.x, Sx[u]);
            Sy[u] = fmaf(w, a0.y, Sy[u]);
            Sz[u] = fmaf(w, a0.z, Sz[u]);
            gx[u] = fmaf(e, a1.x, gx[u]);
            gy[u] = fmaf(e, a1.y, gy[u]);
            gz[u] = fmaf(e, a1.z, gz[u]);
        }
    }

    // ---- write partials: F = Xi*Sw - sum w*Xj  (Xi = X2/2) ----
    float* p = part + (size_t)seg * 6 * N;
    const int iw[MI] = {ia, ib2};
    #pragma unroll
    for (int u = 0; u < MI; ++u) {
        const int i = iw[u];
        if (i < N) {
            p[0 * N + i] = fmaf(0.5f * X2[u], Sw[u], -Sx[u]);
            p[1 * N + i] = fmaf(0.5f * Y2[u], Sw[u], -Sy[u]);
            p[2 * N + i] = fmaf(0.5f * Z2[u], Sw[u], -Sz[u]);
            p[3 * N + i] = gx[u];
            p[4 * N + i] = gy[u];
            p[5 * N + i] = gz[u];
        }
    }
}

__global__ __launch_bounds__(BLOCK)
void lddmm_reduce(const float* __restrict__ part, float* __restrict__ out,
                  int N, int G)
{
    const int i = blockIdx.x * blockDim.x + threadIdx.x;
    if (i >= N) return;
    float s0 = 0.f, s1 = 0.f, s2 = 0.f, s3 = 0.f, s4 = 0.f, s5 = 0.f;
    for (int g = 0; g < G; ++g) {
        const float* p = part + (size_t)g * 6 * N;
        s0 += p[0 * N + i];
        s1 += p[1 * N + i];
        s2 += p[2 * N + i];
        s3 += p[3 * N + i];
        s4 += p[4 * N + i];
        s5 += p[5 * N + i];
    }
    out[i * 3 + 0] = SCALE_F * s0;
    out[i * 3 + 1] = SCALE_F * s1;
    out[i * 3 + 2] = SCALE_F * s2;
    float* o2 = out + (size_t)N * 3;
    o2[i * 3 + 0] = 2.0f * s3;
    o2[i * 3 + 1] = 2.0f * s4;
    o2[i * 3 + 2] = 2.0f * s5;
}

extern "C" void kernel_launch(void* const* d_in, const int* in_sizes, int n_in,
                              void* d_out, int out_size, void* d_ws, size_t ws_size,
                              hipStream_t stream) {
    const float* mom = (const float*)d_in[0];
    const float* pos = (const float*)d_in[1];
    float* out = (float*)d_out;
    const int N = in_sizes[0] / 3;   // B=1, D=3

    int G = 64;
    while (G > 1 && ((N % G) != 0 ||
           (size_t)G * 6 * N * sizeof(float) > ws_size)) G >>= 1;

    const int jlen = N / G;
    const size_t shmem = (size_t)(2 * jlen) * sizeof(float4);  // 8 KiB @ jlen=128
    const int nib = (N + IPB - 1) / IPB;

    lddmm_main<<<dim3(nib * G), dim3(BLOCK), shmem, stream>>>(
        mom, pos, (float*)d_ws, N, G);
    lddmm_reduce<<<dim3((N + BLOCK - 1) / BLOCK), dim3(BLOCK), 0, stream>>>(
        (const float*)d_ws, out, N, G);
}